// Round 2
// baseline (273.851 us; speedup 1.0000x reference)
//
#include <hip/hip_runtime.h>
#include <math.h>

#define NB 4
#define TT 2048
#define EE 768
#define HH 12
#define DD 64
#define NH (NB*HH)                          // 48
#define NT (TT/64)                          // 32 K/V tiles
#define PLANE_S ((size_t)NH * TT * DD)      // 6291456 ushorts per bf16 plane
#define WMAT (EE*EE)                        // 589824
#define XSZ ((size_t)NB * TT * EE)          // 6291456
#define QSCALE 0.18033688011112042f         // 0.125 * log2(e): base-2 softmax

typedef __attribute__((ext_vector_type(8))) short s8b;   // 8 bf16 (4 VGPR)
typedef __attribute__((ext_vector_type(4))) float f4;    // MFMA C/D

// fp32 -> bf16 RNE and hi/lo split: x ~= hi + lo, err ~ 2^-18 |x|
__device__ inline unsigned short bfh(float x) {
    unsigned u = __float_as_uint(x);
    return (unsigned short)((u + 0x7fffu + ((u >> 16) & 1u)) >> 16);
}
__device__ inline float bff(unsigned short s) { return __uint_as_float(((unsigned)s) << 16); }
__device__ inline void split1(float x, unsigned short& h, unsigned short& l) {
    h = bfh(x); l = bfh(x - bff(h));
}
__device__ inline float fexp2(float x) {
#if __has_builtin(__builtin_amdgcn_exp2f)
    return __builtin_amdgcn_exp2f(x);
#else
    return __expf(x * 0.6931471805599453f);
#endif
}
// packed f32x2 -> bf16x2 (RNE), 1 VALU op replacing ~8 of manual bfh+pack
__device__ __forceinline__ unsigned cvtpk(float a, float b) {
    unsigned r;
    asm("v_cvt_pk_bf16_f32 %0, %1, %2" : "=v"(r) : "v"(a), "v"(b));
    return r;
}

// async global->LDS DMA, 16 B per lane. LDS dest = base + lane*16 (HW rule);
// per-lane global gather address carries any swizzle.
__device__ __forceinline__ void async16(const void* g, void* l) {
    __builtin_amdgcn_global_load_lds(
        (const __attribute__((address_space(1))) unsigned int*)g,
        (__attribute__((address_space(3))) unsigned int*)l, 16, 0, 0);
}

// counted vmcnt wait (T4): N loads may stay in flight
template<int N> __device__ __forceinline__ void wait_vm() {
    asm volatile("s_waitcnt vmcnt(%0)" :: "n"(N) : "memory");
}
// raw barrier (no forced vmcnt(0) drain, unlike __syncthreads) with
// compiler memory fences + sched fence so nothing crosses it
__device__ __forceinline__ void bar() {
    asm volatile("" ::: "memory");
    __builtin_amdgcn_s_barrier();
    asm volatile("" ::: "memory");
    __builtin_amdgcn_sched_barrier(0);
}

// ---------------------------------------------------------------------------
// Kernel 0a/0b: pre-split x and W to bf16 hi/lo planes (once).
// ---------------------------------------------------------------------------
__global__ __launch_bounds__(256) void prep_x(
    const float* __restrict__ x, unsigned short* __restrict__ xh,
    unsigned short* __restrict__ xl)
{
    const int base = blockIdx.x * 1024 + threadIdx.x * 4;
    float4 v = *(const float4*)&x[base];
    unsigned short h0,l0,h1,l1,h2,l2,h3,l3;
    split1(v.x,h0,l0); split1(v.y,h1,l1); split1(v.z,h2,l2); split1(v.w,h3,l3);
    *(short4*)&xh[base] = make_short4((short)h0,(short)h1,(short)h2,(short)h3);
    *(short4*)&xl[base] = make_short4((short)l0,(short)l1,(short)l2,(short)l3);
}

__global__ __launch_bounds__(256) void prep_w(
    const float* __restrict__ Wq, const float* __restrict__ Wk,
    const float* __restrict__ Wv, unsigned short* __restrict__ wh,
    unsigned short* __restrict__ wl)
{
    const int mat = blockIdx.y;
    const float* __restrict__ W = (mat == 0) ? Wq : (mat == 1) ? Wk : Wv;
    const int base = blockIdx.x * 1024 + threadIdx.x * 4;
    float4 v = *(const float4*)&W[base];
    unsigned short h0,l0,h1,l1,h2,l2,h3,l3;
    split1(v.x,h0,l0); split1(v.y,h1,l1); split1(v.z,h2,l2); split1(v.w,h3,l3);
    size_t o = (size_t)mat * WMAT + base;
    *(short4*)&wh[o] = make_short4((short)h0,(short)h1,(short)h2,(short)h3);
    *(short4*)&wl[o] = make_short4((short)l0,(short)l1,(short)l2,(short)l3);
}

// ---------------------------------------------------------------------------
// Kernel 1: fused QKV projection (bf16x3 MFMA), counted-vmcnt pipeline.
// Double-buffered A/B LDS (80 KB, 2 blocks/CU). Per K-step: issue next
// step's 10 global_load_lds, s_waitcnt vmcnt(10) (current step's loads
// landed, next step's in flight across both barriers), raw barrier,
// frag reads + 72 MFMA, raw barrier. NO vmcnt(0) drain in the main loop.
// Grid = 512 blocks; blocks 0..255 run two (mt,h) tiles, 256..511 run one
// -> exactly 3 tile-works per CU (balanced, no ragged tail at 2 blocks/CU).
// LDS layout per buffer: row = 64 ushorts = 8 granules of 16 B; logical
// granule g of row r sits at slot j = g ^ (r&7) (XOR bank swizzle folded
// into the per-lane GLOBAL gather address; LDS dest stays linear).
// g<4 = hi plane granule g, g>=4 = lo plane granule g-4.
// ---------------------------------------------------------------------------
__global__ __launch_bounds__(256, 2) void qkv_mfma(
    const unsigned short* __restrict__ xh,
    const unsigned short* __restrict__ xl,
    const unsigned short* __restrict__ whp,
    const unsigned short* __restrict__ wlp,
    unsigned short* __restrict__ ws)
{
    const int tid = threadIdx.x;
    const int w    = tid >> 6;
    const int ln   = tid & 63;
    const int quad = ln >> 4;
    const int lcol = ln & 15;

    union Smem {
        struct { unsigned short A[2][128 * 64]; unsigned short B[2][192 * 64]; } s; // 81920 B
        struct { unsigned short Vh[64][136], Vl[64][136]; } t;                      // 34816 B
    };
    __shared__ __align__(16) union Smem u;

    // DMA lane constants: chunk = 8 rows x 64 ushorts = 1 KB. Lane ln writes
    // LDS (row = c*8 + (ln>>3), slot j = ln&7) <- logical granule
    // g = j ^ (row&7) = (ln&7) ^ (ln>>3); lane-constant across chunks.
    const int rchk = ln >> 3;
    const int gsl  = (ln & 7) ^ rchk;
    const int gk   = (gsl & 3) * 8;                      // k-offset of granule
    const unsigned short* ap = (gsl < 4) ? xh : xl;      // per-lane plane sel
    const unsigned short* bp = (gsl < 4) ? whp : wlp;

    for (int tile = blockIdx.x; tile < 64 * HH; tile += 512) {
        const int mt = tile & 63;       // 0..63
        const int h  = tile >> 6;       // 0..11
        const int m0 = mt * 128;

        __syncthreads();                // prior tile's LDS fully consumed

        f4 acc[3][2][4];
        #pragma unroll
        for (int s = 0; s < 3; ++s)
            #pragma unroll
            for (int rt = 0; rt < 2; ++rt)
                #pragma unroll
                for (int ct = 0; ct < 4; ++ct)
                    acc[s][rt][ct] = f4{0.f, 0.f, 0.f, 0.f};

        auto stage = [&](int kt, int bsel) {
            #pragma unroll
            for (int r = 0; r < 4; ++r) {       // A: 16 KB = 16 chunks, 4/wave
                int c = 4 * w + r;
                async16(ap + (size_t)(m0 + c * 8 + rchk) * EE + kt * 32 + gk,
                        &u.s.A[bsel][c * 512]);
            }
            #pragma unroll
            for (int r = 0; r < 6; ++r) {       // B: 24 KB = 24 chunks, 6/wave
                int cc  = 6 * w + r;
                int mat = cc >> 3;
                int lr  = (cc & 7) * 8 + rchk;
                async16(bp + (size_t)mat * WMAT + (size_t)(h * 64 + lr) * EE + kt * 32 + gk,
                        &u.s.B[bsel][cc * 512]);
            }
        };

        stage(0, 0);
        for (int kt = 0; kt < 24; ++kt) {
            const int cur = kt & 1;
            // buf[cur^1] reads finished at prev iter's exit barrier -> safe
            if (kt + 1 < 24) { stage(kt + 1, cur ^ 1); wait_vm<10>(); }
            else             { wait_vm<0>(); }
            bar();                              // stage(kt) visible to all

            const int jh = (quad ^ (lcol & 7)) * 8;
            s8b ah[2], al[2];
            #pragma unroll
            for (int rt = 0; rt < 2; ++rt) {
                int ab = (w * 32 + rt * 16 + lcol) * 64;
                ah[rt] = *(const s8b*)&u.s.A[cur][ab + jh];
                al[rt] = *(const s8b*)&u.s.A[cur][ab + (jh ^ 32)];  // ^4 gran = lo
            }
            __builtin_amdgcn_s_setprio(1);
            #pragma unroll
            for (int s = 0; s < 3; ++s)
                #pragma unroll
                for (int ct = 0; ct < 4; ++ct) {
                    int bb = (s * 64 + ct * 16 + lcol) * 64;
                    s8b bh = *(const s8b*)&u.s.B[cur][bb + jh];
                    s8b bl = *(const s8b*)&u.s.B[cur][bb + (jh ^ 32)];
                    #pragma unroll
                    for (int rt = 0; rt < 2; ++rt) {
                        acc[s][rt][ct] = __builtin_amdgcn_mfma_f32_16x16x32_bf16(ah[rt], bh, acc[s][rt][ct], 0, 0, 0);
                        acc[s][rt][ct] = __builtin_amdgcn_mfma_f32_16x16x32_bf16(ah[rt], bl, acc[s][rt][ct], 0, 0, 0);
                        acc[s][rt][ct] = __builtin_amdgcn_mfma_f32_16x16x32_bf16(al[rt], bh, acc[s][rt][ct], 0, 0, 0);
                    }
                }
            __builtin_amdgcn_s_setprio(0);
            bar();                              // buf[cur] reads done
        }

        unsigned short* qhp = ws;
        unsigned short* qlp = ws + PLANE_S;
        unsigned short* khp = ws + 2 * PLANE_S;
        unsigned short* klp = ws + 3 * PLANE_S;
        unsigned short* vthp = ws + 4 * PLANE_S;
        unsigned short* vtlp = ws + 5 * PLANE_S;

        const int n = m0 >> 11;
        const int tb = m0 & 2047;
        const int nh = n * HH + h;

        // Q (scaled) and K: direct hi/lo stores, [nh][t][d]
        #pragma unroll
        for (int rt = 0; rt < 2; ++rt)
            #pragma unroll
            for (int reg = 0; reg < 4; ++reg) {
                int t = tb + w * 32 + rt * 16 + quad * 4 + reg;
                size_t ro = ((size_t)nh * TT + t) * DD;
                #pragma unroll
                for (int ct = 0; ct < 4; ++ct) {
                    unsigned short hi, lo;
                    split1(acc[0][rt][ct][reg] * QSCALE, hi, lo);
                    qhp[ro + ct * 16 + lcol] = hi;
                    qlp[ro + ct * 16 + lcol] = lo;
                    split1(acc[1][rt][ct][reg], hi, lo);
                    khp[ro + ct * 16 + lcol] = hi;
                    klp[ro + ct * 16 + lcol] = lo;
                }
            }

        // V: transpose+permute through LDS -> [nh][d][t']
        // slot(u) = (u&15)*4 + (u>>4) within each 64-key group
        __syncthreads();
        #pragma unroll
        for (int rt = 0; rt < 2; ++rt)
            #pragma unroll
            for (int reg = 0; reg < 4; ++reg) {
                int slot = (w >> 1) * 64 + (quad * 4 + reg) * 4 + (w & 1) * 2 + rt;
                #pragma unroll
                for (int ct = 0; ct < 4; ++ct) {
                    unsigned short hi, lo;
                    split1(acc[2][rt][ct][reg], hi, lo);
                    u.t.Vh[ct * 16 + lcol][slot] = hi;
                    u.t.Vl[ct * 16 + lcol][slot] = lo;
                }
            }
        __syncthreads();
        #pragma unroll
        for (int r = 0; r < 8; ++r) {
            int idx = tid + r * 256;
            int pl = idx >> 10, rem = idx & 1023;
            int d = rem >> 4, gg = rem & 15;
            uint4 v = (pl == 0) ? *(const uint4*)&u.t.Vh[d][gg * 8]
                                : *(const uint4*)&u.t.Vl[d][gg * 8];
            unsigned short* dst = (pl == 0) ? vthp : vtlp;
            *(uint4*)&dst[(size_t)nh * (DD * TT) + (size_t)d * TT + tb + gg * 8] = v;
        }
    }
}

// ---------------------------------------------------------------------------
// Kernel 2: MFMA flash attention, counted-vmcnt pipeline (T3/T4), now with
// 3 barriers/tile (merged C+D). Per tile:
//   [vmcnt(4), bar B]  QK            (K[kt] ready; V[kt] still flying)
//   [vmcnt(0), bar C]  stage_k(kt+1) (V[kt] landed AND K reads retired)
//                      SM -> P, PV   (P wave-private: no barrier needed)
//   [bar A]            stage_v(kt+1) (V reads retired)
// K loads always issued before V loads, so vmcnt(4) at B == "K landed,
// V flying". All DMA latency hides under a full compute phase.
// ---------------------------------------------------------------------------
__global__ __launch_bounds__(256, 3) void attn_mfma(
    const unsigned short* __restrict__ ws, float* __restrict__ out)
{
    const int bid = blockIdx.x;          // 0..767
    const int xcd = bid & 7;
    const int r0  = bid >> 3;
    const int qt  = r0 & 15;
    const int nh  = xcd * 6 + (r0 >> 4);
    const int nn  = nh / HH, hh = nh % HH;

    const int tid = threadIdx.x;
    const int w    = tid >> 6;
    const int ln   = tid & 63;
    const int quad = ln >> 4;
    const int lcol = ln & 15;

    const unsigned short* qhp = ws                + (size_t)nh * (TT * DD);
    const unsigned short* qlp = ws +     PLANE_S  + (size_t)nh * (TT * DD);
    const unsigned short* khp = ws + 2 * PLANE_S  + (size_t)nh * (TT * DD);
    const unsigned short* klp = ws + 3 * PLANE_S  + (size_t)nh * (TT * DD);
    const unsigned short* vthp = ws + 4 * PLANE_S + (size_t)nh * (DD * TT);
    const unsigned short* vtlp = ws + 5 * PLANE_S + (size_t)nh * (DD * TT);

    __shared__ __align__(16) unsigned short Kh[64*64], Kl[64*64];
    __shared__ __align__(16) unsigned short Vth[64*64], Vtl[64*64];
    __shared__ __align__(16) unsigned short Pb[128*64];          // P own buf

    // Lane-constant gather offsets (bytes). LDS slot (row, j) receives
    // logical granule g = j ^ (row&7); row = chunk*8 + (ln>>3), j = ln&7.
    const int rchk = ln >> 3;
    const int gsrc = (ln & 7) ^ rchk;
    const int koff = rchk * 128 + gsrc * 16;    // K planes: 128 B rows
    const int voff = rchk * 4096 + gsrc * 16;   // V planes: row stride 4096 B

    // Q fragments (unswizzled global, once)
    s8b qh[2][2], ql[2][2];
    #pragma unroll
    for (int rt = 0; rt < 2; ++rt)
        #pragma unroll
        for (int kk = 0; kk < 2; ++kk) {
            int qrow = qt * 128 + w * 32 + rt * 16 + lcol;
            size_t o = (size_t)qrow * DD + kk * 32 + quad * 8;
            qh[rt][kk] = *(const s8b*)&qhp[o];
            ql[rt][kk] = *(const s8b*)&qlp[o];
        }

    f4 acco[2][4];
    float lsum[2][4];
    #pragma unroll
    for (int rt = 0; rt < 2; ++rt)
        #pragma unroll
        for (int j = 0; j < 4; ++j) { acco[rt][j] = f4{0.f,0.f,0.f,0.f}; lsum[rt][j] = 0.f; }

    // K DMA (4 loads/wave) always issued BEFORE V DMA (4 loads/wave)
    auto stage_k = [&](int kt) {
        #pragma unroll
        for (int r = 0; r < 2; ++r) {
            int c = 2 * w + r;
            async16((const char*)khp + (size_t)kt * 8192 + c * 1024 + koff, &Kh[c * 512]);
            async16((const char*)klp + (size_t)kt * 8192 + c * 1024 + koff, &Kl[c * 512]);
        }
    };
    auto stage_v = [&](int kt) {
        #pragma unroll
        for (int r = 0; r < 2; ++r) {
            int c = 2 * w + r;
            async16((const char*)vthp + (size_t)c * 32768 + kt * 128 + voff, &Vth[c * 512]);
            async16((const char*)vtlp + (size_t)c * 32768 + kt * 128 + voff, &Vtl[c * 512]);
        }
    };

    stage_k(0);
    stage_v(0);

    for (int kt = 0; kt < NT; ++kt) {
        // (B) K[kt] in LDS; V[kt] may still be in flight (4 newest loads)
        wait_vm<4>();
        bar();

        // S - 24 = Q.K^T - 24 (3-term split)
        f4 accs[2][4];
        #pragma unroll
        for (int rt = 0; rt < 2; ++rt)
            #pragma unroll
            for (int ct = 0; ct < 4; ++ct)
                accs[rt][ct] = f4{-24.f, -24.f, -24.f, -24.f};
        __builtin_amdgcn_s_setprio(1);
        #pragma unroll
        for (int kk = 0; kk < 2; ++kk)
            #pragma unroll
            for (int ct = 0; ct < 4; ++ct) {
                int off = (ct * 16 + lcol) * 64 + ((kk * 4 + quad) ^ (lcol & 7)) * 8;
                s8b bh = *(const s8b*)&Kh[off];
                s8b bl = *(const s8b*)&Kl[off];
                #pragma unroll
                for (int rt = 0; rt < 2; ++rt) {
                    accs[rt][ct] = __builtin_amdgcn_mfma_f32_16x16x32_bf16(qh[rt][kk], bh, accs[rt][ct], 0, 0, 0);
                    accs[rt][ct] = __builtin_amdgcn_mfma_f32_16x16x32_bf16(qh[rt][kk], bl, accs[rt][ct], 0, 0, 0);
                    accs[rt][ct] = __builtin_amdgcn_mfma_f32_16x16x32_bf16(ql[rt][kk], bh, accs[rt][ct], 0, 0, 0);
                }
            }
        __builtin_amdgcn_s_setprio(0);

        // (C) V[kt] landed (drain own 4 V loads, issued a full phase ago,
        // hidden under QK) AND all waves' K frag reads retired.
        wait_vm<0>();
        bar();
        if (kt + 1 < NT) stage_k(kt + 1);   // K buffer free; hides under SM+PV

        // p = exp2(s-24); P -> own LDS, b64, permuted slot, swizzled.
        // P rows are wave-private (write+read by same wave only).
        #pragma unroll
        for (int rt = 0; rt < 2; ++rt)
            #pragma unroll
            for (int reg = 0; reg < 4; ++reg) {
                int pr = w * 32 + rt * 16 + quad * 4 + reg;
                float p0 = fexp2(accs[rt][0][reg]);
                float p1 = fexp2(accs[rt][1][reg]);
                float p2 = fexp2(accs[rt][2][reg]);
                float p3 = fexp2(accs[rt][3][reg]);
                lsum[rt][reg] += (p0 + p1) + (p2 + p3);
                int po = pr * 64 + (((lcol >> 1) ^ (pr & 7)) * 8) + (lcol & 1) * 4;
                uint2 pk;
                pk.x = cvtpk(p0, p1);
                pk.y = cvtpk(p2, p3);
                *(uint2*)&Pb[po] = pk;
            }

        // O += P.V (2-term)
        __builtin_amdgcn_s_setprio(1);
        #pragma unroll
        for (int kk = 0; kk < 2; ++kk) {
            s8b pa[2];
            #pragma unroll
            for (int rt = 0; rt < 2; ++rt) {
                int po = (w * 32 + rt * 16 + lcol) * 64 + ((kk * 4 + quad) ^ (lcol & 7)) * 8;
                pa[rt] = *(const s8b*)&Pb[po];
            }
            #pragma unroll
            for (int dt = 0; dt < 4; ++dt) {
                int vo = (dt * 16 + lcol) * 64 + ((kk * 4 + quad) ^ (lcol & 7)) * 8;
                s8b vh = *(const s8b*)&Vth[vo];
                s8b vl = *(const s8b*)&Vtl[vo];
                #pragma unroll
                for (int rt = 0; rt < 2; ++rt) {
                    acco[rt][dt] = __builtin_amdgcn_mfma_f32_16x16x32_bf16(pa[rt], vh, acco[rt][dt], 0, 0, 0);
                    acco[rt][dt] = __builtin_amdgcn_mfma_f32_16x16x32_bf16(pa[rt], vl, acco[rt][dt], 0, 0, 0);
                }
            }
        }
        __builtin_amdgcn_s_setprio(0);

        bar();   // (A) all waves' V reads retired -> V buffer reusable
        if (kt + 1 < NT) stage_v(kt + 1);   // prefetch: hides under QK of kt+1
    }

    // Final: reduce l across the 16 lanes of each quad, normalize, store
    #pragma unroll
    for (int rt = 0; rt < 2; ++rt)
        #pragma unroll
        for (int reg = 0; reg < 4; ++reg) {
            float rs = lsum[rt][reg];
            #pragma unroll
            for (int off = 1; off <= 8; off <<= 1)
                rs += __shfl_xor(rs, off);
            float inv = 1.f / rs;
            int t = qt * 128 + w * 32 + rt * 16 + quad * 4 + reg;
            float* dst = &out[((size_t)(nn * TT + t)) * EE + hh * DD];
            #pragma unroll
            for (int dt = 0; dt < 4; ++dt)
                dst[dt * 16 + lcol] = acco[rt][dt][reg] * inv;
        }
}

// ---------------------------------------------------------------------------
extern "C" void kernel_launch(void* const* d_in, const int* in_sizes, int n_in,
                              void* d_out, int out_size, void* d_ws, size_t ws_size,
                              hipStream_t stream) {
    const float* x  = (const float*)d_in[0];
    const float* Wq = (const float*)d_in[1];
    const float* Wk = (const float*)d_in[2];
    const float* Wv = (const float*)d_in[3];
    float* out = (float*)d_out;
    unsigned short* ws = (unsigned short*)d_ws;
    // ws (ushorts): Qh,Ql,Kh,Kl,Vth,Vtl (6*PLANE_S), Wh,Wl (6*WMAT),
    // xh,xl (2*XSZ). ~102.8 MB.
    unsigned short* whp = ws + 6 * PLANE_S;
    unsigned short* wlp = whp + 3 * (size_t)WMAT;
    unsigned short* xhp = wlp + 3 * (size_t)WMAT;
    unsigned short* xlp = xhp + XSZ;

    dim3 block(256);
    prep_x<<<dim3(6144), block, 0, stream>>>(x, xhp, xlp);
    prep_w<<<dim3(576, 3), block, 0, stream>>>(Wq, Wk, Wv, whp, wlp);
    qkv_mfma<<<dim3(512), block, 0, stream>>>(xhp, xlp, whp, wlp, ws);
    attn_mfma<<<dim3(768), block, 0, stream>>>(ws, out);
}

// Round 3
// 268.645 us; speedup vs baseline: 1.0194x; 1.0194x over previous
//
#include <hip/hip_runtime.h>
#include <math.h>

#define NB 4
#define TT 2048
#define EE 768
#define HH 12
#define DD 64
#define NH (NB*HH)                          // 48
#define NT (TT/64)                          // 32 K/V tiles
#define PLANE_S ((size_t)NH * TT * DD)      // 6291456 ushorts per bf16 plane
#define WMAT (EE*EE)                        // 589824
#define XSZ ((size_t)NB * TT * EE)          // 6291456
#define QSCALE 0.18033688011112042f         // 0.125 * log2(e): base-2 softmax

typedef __attribute__((ext_vector_type(8))) short s8b;   // 8 bf16 (4 VGPR)
typedef __attribute__((ext_vector_type(4))) float f4;    // MFMA C/D

// fp32 -> bf16 RNE and hi/lo split: x ~= hi + lo, err ~ 2^-18 |x|
__device__ inline unsigned short bfh(float x) {
    unsigned u = __float_as_uint(x);
    return (unsigned short)((u + 0x7fffu + ((u >> 16) & 1u)) >> 16);
}
__device__ inline float bff(unsigned short s) { return __uint_as_float(((unsigned)s) << 16); }
__device__ inline void split1(float x, unsigned short& h, unsigned short& l) {
    h = bfh(x); l = bfh(x - bff(h));
}
__device__ inline float fexp2(float x) {
#if __has_builtin(__builtin_amdgcn_exp2f)
    return __builtin_amdgcn_exp2f(x);
#else
    return __expf(x * 0.6931471805599453f);
#endif
}
// packed f32x2 -> bf16x2 (RNE): low16 = bf16(a), high16 = bf16(b)
__device__ __forceinline__ unsigned cvtpk(float a, float b) {
    unsigned r;
    asm("v_cvt_pk_bf16_f32 %0, %1, %2" : "=v"(r) : "v"(a), "v"(b));
    return r;
}
// gfx950 cross-lane half-swaps. pl32: a.hi32lanes <-> b.lo32lanes.
// pl16: a's odd 16-lane rows <-> b's even 16-lane rows.
__device__ __forceinline__ void pl32(unsigned& a, unsigned& b) {
    asm("v_permlane32_swap_b32 %0, %1" : "+v"(a), "+v"(b));
}
__device__ __forceinline__ void pl16(unsigned& a, unsigned& b) {
    asm("v_permlane16_swap_b32 %0, %1" : "+v"(a), "+v"(b));
}

// async global->LDS DMA, 16 B per lane. LDS dest = base + lane*16 (HW rule);
// per-lane global gather address carries any swizzle.
__device__ __forceinline__ void async16(const void* g, void* l) {
    __builtin_amdgcn_global_load_lds(
        (const __attribute__((address_space(1))) unsigned int*)g,
        (__attribute__((address_space(3))) unsigned int*)l, 16, 0, 0);
}

// counted vmcnt wait (T4): N loads may stay in flight
template<int N> __device__ __forceinline__ void wait_vm() {
    asm volatile("s_waitcnt vmcnt(%0)" :: "n"(N) : "memory");
}
// raw barrier (no forced vmcnt(0) drain, unlike __syncthreads)
__device__ __forceinline__ void bar() {
    asm volatile("" ::: "memory");
    __builtin_amdgcn_s_barrier();
    asm volatile("" ::: "memory");
    __builtin_amdgcn_sched_barrier(0);
}

// ---------------------------------------------------------------------------
// Kernel 0: pre-split x and W to bf16 hi/lo planes (merged: one launch).
// blocks [0,6144): x; blocks [6144,7872): W (576 per matrix).
// ---------------------------------------------------------------------------
__global__ __launch_bounds__(256) void prep(
    const float* __restrict__ x,
    const float* __restrict__ Wq, const float* __restrict__ Wk,
    const float* __restrict__ Wv,
    unsigned short* __restrict__ xh, unsigned short* __restrict__ xl,
    unsigned short* __restrict__ wh, unsigned short* __restrict__ wl)
{
    const int bid = blockIdx.x;
    const float* __restrict__ src;
    unsigned short *dh, *dl;
    int base;
    if (bid < 6144) {
        base = bid * 1024 + threadIdx.x * 4;
        src = x; dh = xh; dl = xl;
    } else {
        const int b2 = bid - 6144;
        const int mat = b2 / 576;
        base = (b2 % 576) * 1024 + threadIdx.x * 4;
        src = (mat == 0) ? Wq : (mat == 1) ? Wk : Wv;
        dh = wh + (size_t)mat * WMAT; dl = wl + (size_t)mat * WMAT;
    }
    float4 v = *(const float4*)&src[base];
    unsigned short h0,l0,h1,l1,h2,l2,h3,l3;
    split1(v.x,h0,l0); split1(v.y,h1,l1); split1(v.z,h2,l2); split1(v.w,h3,l3);
    *(short4*)&dh[base] = make_short4((short)h0,(short)h1,(short)h2,(short)h3);
    *(short4*)&dl[base] = make_short4((short)l0,(short)l1,(short)l2,(short)l3);
}

// ---------------------------------------------------------------------------
// Kernel 1: fused QKV projection (bf16x3 MFMA), global_load_lds staging into
// an unpadded combined hi/lo LDS tile (round-1 variant: 40 KB, 3 blocks/CU).
// Row = 64 ushorts = 8 granules of 16 B; logical granule g of row r sits at
// slot j = g ^ (r&7) (XOR bank swizzle folded into the per-lane GLOBAL
// gather address; LDS dest stays linear). g<4 = hi granule g, g>=4 = lo g-4.
// V is stored transposed [nh][d][t] with IDENTITY key order (attn's P is now
// produced in true key order in-register).
// ---------------------------------------------------------------------------
__global__ __launch_bounds__(256, 3) void qkv_mfma(
    const unsigned short* __restrict__ xh,
    const unsigned short* __restrict__ xl,
    const unsigned short* __restrict__ whp,
    const unsigned short* __restrict__ wlp,
    unsigned short* __restrict__ ws)
{
    const int mt  = blockIdx.x;     // 0..63
    const int h   = blockIdx.y;     // 0..11
    const int tid = threadIdx.x;
    const int w    = tid >> 6;
    const int ln   = tid & 63;
    const int quad = ln >> 4;
    const int lcol = ln & 15;

    union Smem {
        struct { unsigned short A[128 * 64], B[3 * 64 * 64]; } s;  // 40960 B
        struct { unsigned short Vh[64][136], Vl[64][136]; } t;     // 34816 B
    };
    __shared__ __align__(16) union Smem u;

    f4 acc[3][2][4];
    #pragma unroll
    for (int s = 0; s < 3; ++s)
        #pragma unroll
        for (int rt = 0; rt < 2; ++rt)
            #pragma unroll
            for (int ct = 0; ct < 4; ++ct)
                acc[s][rt][ct] = f4{0.f, 0.f, 0.f, 0.f};

    const int m0 = mt * 128;
    // DMA lane constants: chunk = 8 rows x 64 ushorts = 1 KB. Lane ln writes
    // LDS (row = c*8 + (ln>>3), slot j = ln&7) <- logical granule
    // g = j ^ (row&7) = (ln&7) ^ (ln>>3); lane-constant across chunks.
    const int rchk = ln >> 3;
    const int gsl  = (ln & 7) ^ rchk;
    const int gk   = (gsl & 3) * 8;                      // k-offset of granule
    const unsigned short* ap = (gsl < 4) ? xh : xl;      // per-lane plane sel
    const unsigned short* bp = (gsl < 4) ? whp : wlp;

    for (int kt = 0; kt < EE; kt += 32) {
        __syncthreads();                    // prev frag reads done
        #pragma unroll
        for (int r = 0; r < 4; ++r) {       // A: 16 KB = 16 chunks, 4/wave
            int c = 4 * w + r;
            async16(ap + (size_t)(m0 + c * 8 + rchk) * EE + kt + gk,
                    &u.s.A[c * 512]);
        }
        #pragma unroll
        for (int r = 0; r < 6; ++r) {       // B: 24 KB = 24 chunks, 6/wave
            int cc  = 6 * w + r;
            int mat = cc >> 3;
            int lr  = (cc & 7) * 8 + rchk;
            async16(bp + (size_t)mat * WMAT + (size_t)(h * 64 + lr) * EE + kt + gk,
                    &u.s.B[cc * 512]);
        }
        __syncthreads();                    // vmcnt(0) drain -> tile visible

        const int jh = (quad ^ (lcol & 7)) * 8;
        s8b ah[2], al[2];
        #pragma unroll
        for (int rt = 0; rt < 2; ++rt) {
            int ab = (w * 32 + rt * 16 + lcol) * 64;
            ah[rt] = *(const s8b*)&u.s.A[ab + jh];
            al[rt] = *(const s8b*)&u.s.A[ab + (jh ^ 32)];   // ^4 granules = lo
        }
        __builtin_amdgcn_s_setprio(1);
        #pragma unroll
        for (int s = 0; s < 3; ++s)
            #pragma unroll
            for (int ct = 0; ct < 4; ++ct) {
                int bb = (s * 64 + ct * 16 + lcol) * 64;
                s8b bh = *(const s8b*)&u.s.B[bb + jh];
                s8b bl = *(const s8b*)&u.s.B[bb + (jh ^ 32)];
                #pragma unroll
                for (int rt = 0; rt < 2; ++rt) {
                    acc[s][rt][ct] = __builtin_amdgcn_mfma_f32_16x16x32_bf16(ah[rt], bh, acc[s][rt][ct], 0, 0, 0);
                    acc[s][rt][ct] = __builtin_amdgcn_mfma_f32_16x16x32_bf16(ah[rt], bl, acc[s][rt][ct], 0, 0, 0);
                    acc[s][rt][ct] = __builtin_amdgcn_mfma_f32_16x16x32_bf16(al[rt], bh, acc[s][rt][ct], 0, 0, 0);
                }
            }
        __builtin_amdgcn_s_setprio(0);
    }

    unsigned short* qhp = ws;
    unsigned short* qlp = ws + PLANE_S;
    unsigned short* khp = ws + 2 * PLANE_S;
    unsigned short* klp = ws + 3 * PLANE_S;
    unsigned short* vthp = ws + 4 * PLANE_S;
    unsigned short* vtlp = ws + 5 * PLANE_S;

    const int n = m0 >> 11;
    const int tb = m0 & 2047;
    const int nh = n * HH + h;

    // Q (scaled) and K: direct hi/lo stores, [nh][t][d]
    #pragma unroll
    for (int rt = 0; rt < 2; ++rt)
        #pragma unroll
        for (int reg = 0; reg < 4; ++reg) {
            int t = tb + w * 32 + rt * 16 + quad * 4 + reg;
            size_t ro = ((size_t)nh * TT + t) * DD;
            #pragma unroll
            for (int ct = 0; ct < 4; ++ct) {
                unsigned short hi, lo;
                split1(acc[0][rt][ct][reg] * QSCALE, hi, lo);
                qhp[ro + ct * 16 + lcol] = hi;
                qlp[ro + ct * 16 + lcol] = lo;
                split1(acc[1][rt][ct][reg], hi, lo);
                khp[ro + ct * 16 + lcol] = hi;
                klp[ro + ct * 16 + lcol] = lo;
            }
        }

    // V: transpose through LDS -> [nh][d][t], IDENTITY key order
    __syncthreads();
    #pragma unroll
    for (int rt = 0; rt < 2; ++rt)
        #pragma unroll
        for (int reg = 0; reg < 4; ++reg) {
            int slot = (w >> 1) * 64 + (w & 1) * 32 + rt * 16 + quad * 4 + reg;
            #pragma unroll
            for (int ct = 0; ct < 4; ++ct) {
                unsigned short hi, lo;
                split1(acc[2][rt][ct][reg], hi, lo);
                u.t.Vh[ct * 16 + lcol][slot] = hi;
                u.t.Vl[ct * 16 + lcol][slot] = lo;
            }
        }
    __syncthreads();
    #pragma unroll
    for (int r = 0; r < 8; ++r) {
        int idx = tid + r * 256;
        int pl = idx >> 10, rem = idx & 1023;
        int d = rem >> 4, gg = rem & 15;
        uint4 v = (pl == 0) ? *(const uint4*)&u.t.Vh[d][gg * 8]
                            : *(const uint4*)&u.t.Vl[d][gg * 8];
        unsigned short* dst = (pl == 0) ? vthp : vtlp;
        *(uint4*)&dst[(size_t)nh * (DD * TT) + (size_t)d * TT + tb + gg * 8] = v;
    }
}

// ---------------------------------------------------------------------------
// Kernel 2: MFMA flash attention, counted-vmcnt pipeline + in-register P.
// QK is computed SWAPPED: accs = mfma(A=K_frag, B=Q_frag) -> C layout
// col=lcol=query, row=quad*4+reg=key. Each lane then owns P[q=lcol][16 keys],
// and the PV A-fragment (keys quad*8..+7 per kk) is produced entirely in
// registers: 16 cvt_pk_bf16 + 16 permlane{32,16}_swap per wave-tile.
// This deletes the P LDS round-trip (8 ds_write + 4 ds_read per wave-tile)
// and the 16 KB P buffer (LDS 48->32 KB). Barriers/tile: 3, no vmcnt(0)
// drain in steady state (K issued before V => vmcnt(4) at B = K landed).
// ---------------------------------------------------------------------------
__global__ __launch_bounds__(256, 3) void attn_mfma(
    const unsigned short* __restrict__ ws, float* __restrict__ out)
{
    const int bid = blockIdx.x;          // 0..767
    const int xcd = bid & 7;
    const int r0  = bid >> 3;
    const int qt  = r0 & 15;
    const int nh  = xcd * 6 + (r0 >> 4);
    const int nn  = nh / HH, hh = nh % HH;

    const int tid = threadIdx.x;
    const int w    = tid >> 6;
    const int ln   = tid & 63;
    const int quad = ln >> 4;
    const int lcol = ln & 15;

    const unsigned short* qhp = ws                + (size_t)nh * (TT * DD);
    const unsigned short* qlp = ws +     PLANE_S  + (size_t)nh * (TT * DD);
    const unsigned short* khp = ws + 2 * PLANE_S  + (size_t)nh * (TT * DD);
    const unsigned short* klp = ws + 3 * PLANE_S  + (size_t)nh * (TT * DD);
    const unsigned short* vthp = ws + 4 * PLANE_S + (size_t)nh * (DD * TT);
    const unsigned short* vtlp = ws + 5 * PLANE_S + (size_t)nh * (DD * TT);

    __shared__ __align__(16) unsigned short Kh[64*64], Kl[64*64];
    __shared__ __align__(16) unsigned short Vth[64*64], Vtl[64*64];

    // Lane-constant gather offsets (bytes). LDS slot (row, j) receives
    // logical granule g = j ^ (row&7); row = chunk*8 + (ln>>3), j = ln&7.
    const int rchk = ln >> 3;
    const int gsrc = (ln & 7) ^ rchk;
    const int koff = rchk * 128 + gsrc * 16;    // K planes: 128 B rows
    const int voff = rchk * 4096 + gsrc * 16;   // V planes: row stride 4096 B

    // Q fragments (unswizzled global, once)
    s8b qh[2][2], ql[2][2];
    #pragma unroll
    for (int rt = 0; rt < 2; ++rt)
        #pragma unroll
        for (int kk = 0; kk < 2; ++kk) {
            int qrow = qt * 128 + w * 32 + rt * 16 + lcol;
            size_t o = (size_t)qrow * DD + kk * 32 + quad * 8;
            qh[rt][kk] = *(const s8b*)&qhp[o];
            ql[rt][kk] = *(const s8b*)&qlp[o];
        }

    f4 acco[2][4];
    float lsum[2];
    #pragma unroll
    for (int rt = 0; rt < 2; ++rt) {
        lsum[rt] = 0.f;
        #pragma unroll
        for (int j = 0; j < 4; ++j) acco[rt][j] = f4{0.f,0.f,0.f,0.f};
    }

    // K DMA (4 loads/wave) always issued BEFORE V DMA (4 loads/wave)
    auto stage_k = [&](int kt) {
        #pragma unroll
        for (int r = 0; r < 2; ++r) {
            int c = 2 * w + r;
            async16((const char*)khp + (size_t)kt * 8192 + c * 1024 + koff, &Kh[c * 512]);
            async16((const char*)klp + (size_t)kt * 8192 + c * 1024 + koff, &Kl[c * 512]);
        }
    };
    auto stage_v = [&](int kt) {
        #pragma unroll
        for (int r = 0; r < 2; ++r) {
            int c = 2 * w + r;
            async16((const char*)vthp + (size_t)c * 32768 + kt * 128 + voff, &Vth[c * 512]);
            async16((const char*)vtlp + (size_t)c * 32768 + kt * 128 + voff, &Vtl[c * 512]);
        }
    };

    stage_k(0);
    stage_v(0);

    for (int kt = 0; kt < NT; ++kt) {
        // (B) K[kt] in LDS; V[kt] may still be in flight (4 newest loads)
        wait_vm<4>();
        bar();

        // S^T - 24: accs = K.Q^T - 24 (3-term split), col=query row=key
        f4 accs[2][4];
        #pragma unroll
        for (int rt = 0; rt < 2; ++rt)
            #pragma unroll
            for (int ct = 0; ct < 4; ++ct)
                accs[rt][ct] = f4{-24.f, -24.f, -24.f, -24.f};
        __builtin_amdgcn_s_setprio(1);
        #pragma unroll
        for (int kk = 0; kk < 2; ++kk)
            #pragma unroll
            for (int ct = 0; ct < 4; ++ct) {
                int off = (ct * 16 + lcol) * 64 + ((kk * 4 + quad) ^ (lcol & 7)) * 8;
                s8b bh = *(const s8b*)&Kh[off];
                s8b bl = *(const s8b*)&Kl[off];
                #pragma unroll
                for (int rt = 0; rt < 2; ++rt) {
                    accs[rt][ct] = __builtin_amdgcn_mfma_f32_16x16x32_bf16(bh, qh[rt][kk], accs[rt][ct], 0, 0, 0);
                    accs[rt][ct] = __builtin_amdgcn_mfma_f32_16x16x32_bf16(bl, qh[rt][kk], accs[rt][ct], 0, 0, 0);
                    accs[rt][ct] = __builtin_amdgcn_mfma_f32_16x16x32_bf16(bh, ql[rt][kk], accs[rt][ct], 0, 0, 0);
                }
            }
        __builtin_amdgcn_s_setprio(0);

        // (C) V[kt] landed (drain own 4 V loads, issued a full phase ago,
        // hidden under QK) AND all waves' K frag reads retired.
        wait_vm<0>();
        bar();
        if (kt + 1 < NT) stage_k(kt + 1);   // K buffer free; hides under SM+PV

        // p = exp2(s-24); build PV A-frags fully in registers.
        // Lane (lcol,quad_s) holds P[q=lcol][key = ct*16 + quad_s*4 + reg].
        // Target lane (lcol,quad_t) needs keys kk*32 + quad_t*8 + j, j=0..7.
        // With X=w01[2kk],Y=w23[2kk],Z=w01[2kk+1],W=w23[2kk+1]:
        // pl32 then pl16 on (X,Z) yields word0=[X0,X2,Z0,Z2], word2=[X1,X3,Z1,Z3];
        // (Y,W) likewise gives word1/word3. 16 cvtpk + 16 permlane per tile.
        s8b pa[2][2];
        #pragma unroll
        for (int rt = 0; rt < 2; ++rt) {
            float p[4][4];
            float s = 0.f;
            #pragma unroll
            for (int ct = 0; ct < 4; ++ct) {
                #pragma unroll
                for (int reg = 0; reg < 4; ++reg) {
                    p[ct][reg] = fexp2(accs[rt][ct][reg]);
                    s += p[ct][reg];
                }
            }
            lsum[rt] += s;
            unsigned w01[4], w23[4];
            #pragma unroll
            for (int ct = 0; ct < 4; ++ct) {
                w01[ct] = cvtpk(p[ct][0], p[ct][1]);
                w23[ct] = cvtpk(p[ct][2], p[ct][3]);
            }
            #pragma unroll
            for (int kk = 0; kk < 2; ++kk) {
                unsigned a0 = w01[2*kk], b0 = w01[2*kk+1];
                unsigned a1 = w23[2*kk], b1 = w23[2*kk+1];
                pl32(a0, b0); pl16(a0, b0);   // a0=word0, b0=word2
                pl32(a1, b1); pl16(a1, b1);   // a1=word1, b1=word3
                union { unsigned u[4]; s8b v; } pk;
                pk.u[0] = a0; pk.u[1] = a1; pk.u[2] = b0; pk.u[3] = b1;
                pa[rt][kk] = pk.v;
            }
        }

        // O += P.V (2-term), A-frags in registers
        __builtin_amdgcn_s_setprio(1);
        #pragma unroll
        for (int kk = 0; kk < 2; ++kk) {
            #pragma unroll
            for (int dt = 0; dt < 4; ++dt) {
                int vo = (dt * 16 + lcol) * 64 + ((kk * 4 + quad) ^ (lcol & 7)) * 8;
                s8b vh = *(const s8b*)&Vth[vo];
                s8b vl = *(const s8b*)&Vtl[vo];
                #pragma unroll
                for (int rt = 0; rt < 2; ++rt) {
                    acco[rt][dt] = __builtin_amdgcn_mfma_f32_16x16x32_bf16(pa[rt][kk], vh, acco[rt][dt], 0, 0, 0);
                    acco[rt][dt] = __builtin_amdgcn_mfma_f32_16x16x32_bf16(pa[rt][kk], vl, acco[rt][dt], 0, 0, 0);
                }
            }
        }
        __builtin_amdgcn_s_setprio(0);

        bar();   // (A) all waves' V reads retired -> V buffer reusable
        if (kt + 1 < NT) stage_v(kt + 1);   // prefetch: hides under QK of kt+1
    }

    // Final: lane holds lsum for q=lcol; reduce over quads, redistribute
    // denominators to the C-layout rows (q = quad*4+reg) via shfl.
    #pragma unroll
    for (int rt = 0; rt < 2; ++rt) {
        float rs = lsum[rt];
        rs += __shfl_xor(rs, 16);
        rs += __shfl_xor(rs, 32);
        #pragma unroll
        for (int reg = 0; reg < 4; ++reg) {
            float inv = 1.f / __shfl(rs, quad * 4 + reg);
            int t = qt * 128 + w * 32 + rt * 16 + quad * 4 + reg;
            float* dst = &out[((size_t)(nn * TT + t)) * EE + hh * DD];
            #pragma unroll
            for (int dt = 0; dt < 4; ++dt)
                dst[dt * 16 + lcol] = acco[rt][dt][reg] * inv;
        }
    }
}

// ---------------------------------------------------------------------------
extern "C" void kernel_launch(void* const* d_in, const int* in_sizes, int n_in,
                              void* d_out, int out_size, void* d_ws, size_t ws_size,
                              hipStream_t stream) {
    const float* x  = (const float*)d_in[0];
    const float* Wq = (const float*)d_in[1];
    const float* Wk = (const float*)d_in[2];
    const float* Wv = (const float*)d_in[3];
    float* out = (float*)d_out;
    unsigned short* ws = (unsigned short*)d_ws;
    // ws (ushorts): Qh,Ql,Kh,Kl,Vth,Vtl (6*PLANE_S), Wh,Wl (6*WMAT),
    // xh,xl (2*XSZ). ~102.8 MB.
    unsigned short* whp = ws + 6 * PLANE_S;
    unsigned short* wlp = whp + 3 * (size_t)WMAT;
    unsigned short* xhp = wlp + 3 * (size_t)WMAT;
    unsigned short* xlp = xhp + XSZ;

    dim3 block(256);
    prep<<<dim3(7872), block, 0, stream>>>(x, Wq, Wk, Wv, xhp, xlp, whp, wlp);
    qkv_mfma<<<dim3(64, 12), block, 0, stream>>>(xhp, xlp, whp, wlp, ws);
    attn_mfma<<<dim3(768), block, 0, stream>>>(ws, out);
}